// Round 17
// baseline (54.183 us; speedup 1.0000x reference)
//
#include <hip/hip_runtime.h>
#include <math.h>

#define NM 16
#define VMAX 1080
#define UMAX 1920
#define WPR (UMAX/32)          // 60 words per row
#define FGN 2048
#define BGN 2048
#define NPT (FGN+BGN)          // 4096
#define PTS_FLOATS (NM*NPT*8)  // 524288

// ---- workspace layout (bytes) ----
#define OFF_BITMAP  0
#define BMBYTES     (NM*VMAX*WPR*4)
#define OFF_PP      (OFF_BITMAP + BMBYTES)   // per-row inclusive word-popcount prefix
#define OFF_ROWCNT  (OFF_PP + BMBYTES)
#define OFF_RUSUM   (OFF_ROWCNT + NM*VMAX*4)
#define OFF_RUMIN   (OFF_RUSUM  + NM*VMAX*4)
#define OFF_RUMAX   (OFF_RUMIN  + NM*VMAX*4)
// end ~8.8 MB

struct SInfo {
  int v0e, v1e, u0e, u1e, cnt_fg, v0m, v1m;
  float cntf, vc, uc;
};

__device__ inline unsigned int rangemask(int widx, int a, int b) {
  int lo = widx << 5, hi = lo + 32;
  if (b <= lo || a >= hi) return 0u;
  unsigned int m = 0xFFFFFFFFu;
  if (a > lo) m &= 0xFFFFFFFFu << (a - lo);
  if (b < hi) m &= (1u << (b - lo)) - 1u;
  return m;
}

// Block = 256 threads = 4 rows of one mask (contiguous 30720 B).
// Pass 1: fully-coalesced linear uint4 loads (adjacent lanes adjacent 16 B);
//         each uint4 -> 4-bit nibble; 8-lane shfl-OR tree packs a word -> LDS.
// Pass 2: wave r reads row r from LDS (lane=word, conflict-free) and computes
//         stats + PP with the proven (bit-identical) code, coalesced stores.
__global__ __launch_bounds__(256) void k_rows(const unsigned int* __restrict__ masks,
                                              char* ws) {
  __shared__ unsigned int s_bm[4 * WPR];   // 240 words
  const int tid = threadIdx.x, wid = tid >> 6, lane = tid & 63;
  const int R0 = blockIdx.x * 4;           // first row of this block
  const uint4* base = (const uint4*)(masks + (long long)R0 * UMAX);

  #pragma unroll
  for (int j = 0; j < 8; j++) {
    const int idx = j * 256 + tid;         // uint4 index in [0,1920)
    unsigned int val = 0;
    if (idx < 4 * UMAX / 4) {              // 1920
      uint4 x = base[idx];
      unsigned int nib = (x.x ? 1u : 0u) | (x.y ? 2u : 0u) | (x.z ? 4u : 0u) | (x.w ? 8u : 0u);
      val = nib << ((tid & 7) * 4);
    }
    // OR-reduce within each 8-lane group
    val |= __shfl_xor(val, 1);
    val |= __shfl_xor(val, 2);
    val |= __shfl_xor(val, 4);
    if ((tid & 7) == 0 && idx < 4 * UMAX / 4)
      s_bm[j * 32 + (tid >> 3)] = val;
  }
  __syncthreads();

  // pass 2: wave wid owns row R0 + wid
  const int R = R0 + wid;
  const int w = lane;
  unsigned int word = (w < WPR) ? s_bm[wid * WPR + w] : 0u;
  if (w < WPR)
    ((unsigned int*)(ws + OFF_BITMAP))[(long long)R * WPR + w] = word;

  const int pc = __popc(word);
  // inclusive prefix of word popcounts across lanes -> PP
  int I = pc;
  for (int d = 1; d < 64; d <<= 1) { int t = __shfl_up(I, d); if (lane >= d) I += t; }
  if (w < WPR) ((int*)(ws + OFF_PP))[(long long)R * WPR + w] = I;

  int cnt = pc;
  int usum = 0, umin = 0x7FFFFFFF, umax = -1;
  if (word) {
    umin = (w << 5) + __ffs(word) - 1;
    umax = (w << 5) + 31 - __clz(word);
    int bitsum = __popc(word & 0xAAAAAAAAu)
               + 2  * __popc(word & 0xCCCCCCCCu)
               + 4  * __popc(word & 0xF0F0F0F0u)
               + 8  * __popc(word & 0xFF00FF00u)
               + 16 * __popc(word & 0xFFFF0000u);
    usum = (w << 5) * cnt + bitsum;
  }
  for (int off = 32; off > 0; off >>= 1) {
    cnt  += __shfl_xor(cnt, off);
    usum += __shfl_xor(usum, off);
    umin = min(umin, __shfl_xor(umin, off));
    umax = max(umax, __shfl_xor(umax, off));
  }
  if (lane == 0) {
    ((int*)(ws + OFF_ROWCNT))[R] = cnt;
    ((int*)(ws + OFF_RUSUM))[R] = usum;
    ((int*)(ws + OFF_RUMIN))[R] = umin;
    ((int*)(ws + OFF_RUMAX))[R] = umax;
  }
}

// 256 blocks x 256 threads; 16 blocks per mask (8 fg + 8 bg), 256 queries each.
// Phase A: per-block bbox/centroid/crop reduce (redundant, L2-hot).
// Phase B: in-LDS two-level prefix scan; bg row counts O(1) via PP.
// Phase C: 256 rank-select queries (bit-exact logic).
__global__ __launch_bounds__(256) void k_samp(const float* __restrict__ img,
                                              const float* __restrict__ ufg,
                                              const float* __restrict__ ubg,
                                              const float* __restrict__ cat,
                                              char* ws, float* __restrict__ out) {
  __shared__ int s_p[VMAX + 1];
  __shared__ int s_wt[4];
  __shared__ long long s_vs[4], s_us[4];
  __shared__ int s_cnt[4], s_v0[4], s_v1[4], s_u0[4], s_u1[4];
  __shared__ SInfo smi;
  const int n = blockIdx.x >> 4, sub = blockIdx.x & 15;
  const bool isfg = sub < 8;
  const int tid = threadIdx.x, wid = tid >> 6, lane = tid & 63;
  const int* rowcnt = (const int*)(ws + OFF_ROWCNT) + n * VMAX;
  const int* rusum  = (const int*)(ws + OFF_RUSUM)  + n * VMAX;
  const int* rumin  = (const int*)(ws + OFF_RUMIN)  + n * VMAX;
  const int* rumax  = (const int*)(ws + OFF_RUMAX)  + n * VMAX;
  const unsigned int* bmall = (const unsigned int*)(ws + OFF_BITMAP);
  const unsigned int* bmn = bmall + (long long)n * VMAX * WPR;
  const int* ppn = (const int*)(ws + OFF_PP) + (long long)n * VMAX * WPR;

  // ---- phase A: bbox + centroid reduce ----
  {
    int cnt = 0, v0 = 0x7FFFFFFF, v1 = -1, u0 = 0x7FFFFFFF, u1 = -1;
    long long vsum = 0, usum = 0;
    for (int v = tid; v < VMAX; v += 256) {
      int c = rowcnt[v];
      if (c > 0) { v0 = min(v0, v); v1 = max(v1, v); u0 = min(u0, rumin[v]); u1 = max(u1, rumax[v]); }
      cnt += c; vsum += (long long)c * v; usum += (long long)rusum[v];
    }
    for (int off = 32; off > 0; off >>= 1) {
      cnt  += __shfl_xor(cnt, off);
      vsum += __shfl_xor(vsum, off);
      usum += __shfl_xor(usum, off);
      v0 = min(v0, __shfl_xor(v0, off));
      v1 = max(v1, __shfl_xor(v1, off));
      u0 = min(u0, __shfl_xor(u0, off));
      u1 = max(u1, __shfl_xor(u1, off));
    }
    if (lane == 0) {
      s_cnt[wid] = cnt; s_vs[wid] = vsum; s_us[wid] = usum;
      s_v0[wid] = v0; s_v1[wid] = v1; s_u0[wid] = u0; s_u1[wid] = u1;
    }
    __syncthreads();
    if (wid == 0) {
      int c2 = (lane < 4) ? s_cnt[lane] : 0;
      long long vs2 = (lane < 4) ? s_vs[lane] : 0, us2 = (lane < 4) ? s_us[lane] : 0;
      int a0 = (lane < 4) ? s_v0[lane] : 0x7FFFFFFF, a1 = (lane < 4) ? s_v1[lane] : -1;
      int b0 = (lane < 4) ? s_u0[lane] : 0x7FFFFFFF, b1 = (lane < 4) ? s_u1[lane] : -1;
      for (int off = 1; off <= 2; off <<= 1) {
        c2 += __shfl_xor(c2, off);
        vs2 += __shfl_xor(vs2, off);
        us2 += __shfl_xor(us2, off);
        a0 = min(a0, __shfl_xor(a0, off));
        a1 = max(a1, __shfl_xor(a1, off));
        b0 = min(b0, __shfl_xor(b0, off));
        b1 = max(b1, __shfl_xor(b1, off));
      }
      if (lane == 0) {
        int vlen = a1 + 1 - a0, ulen = b1 + 1 - b0;
        int dv = (int)floorf(0.2f * (float)vlen);      // replicate f32 floor exactly
        int du = (int)floorf(0.2f * (float)ulen);
        smi.v0e = max(0, a0 - dv); smi.v1e = min(a1 + 1 + dv, VMAX - 1);
        smi.u0e = max(0, b0 - du); smi.u1e = min(b1 + 1 + du, UMAX - 1);
        smi.cnt_fg = c2; smi.cntf = (float)c2;
        smi.vc = (float)((double)vs2 / (double)c2) - (float)smi.v0e;
        smi.uc = (float)((double)us2 / (double)c2) - (float)smi.u0e;
        smi.v0m = a0; smi.v1m = a1;
        if (sub == 0) {
          float* xy = out + PTS_FLOATS + n * 4;
          xy[0] = (float)b0 / (float)UMAX; xy[1] = (float)a0 / (float)VMAX;
          xy[2] = (float)b1 / (float)UMAX; xy[3] = (float)a1 / (float)VMAX;
        }
      }
    }
    __syncthreads();
  }

  // ---- phase B: two-level scan into s_p[0..1080] (bg rows O(1) via PP) ----
  {
    const int a = smi.u0e, b = smi.u1e;
    const int wlo = a >> 5, whi = (b > a) ? ((b - 1) >> 5) : wlo;
    int wbase = 0;
    for (int c = 0; c < 270; c += 64) {
      const int act = (c + lane) < 270;
      const int r = wid * 270 + c + lane;
      int s = 0;
      if (act) {
        if (isfg) {
          s = rowcnt[r];
        } else if (r >= smi.v0e && r < smi.v1e && b > a) {
          const unsigned int* row = bmn + (long long)r * WPR;
          const int* Ip = ppn + (long long)r * WPR;
          int cm;
          if (whi == wlo) {
            cm = __popc(row[wlo] & rangemask(wlo, a, b));
          } else {
            cm = __popc(row[wlo] & rangemask(wlo, a, b))
               + __popc(row[whi] & rangemask(whi, a, b))
               + (Ip[whi - 1] - Ip[wlo]);
          }
          s = (b - a) - cm;
        }
      }
      for (int d = 1; d < 64; d <<= 1) { int t = __shfl_up(s, d); if (lane >= d) s += t; }
      if (act) s_p[r + 1] = wbase + s;
      wbase += __shfl(s, 63);
    }
    if (lane == 0) s_wt[wid] = wbase;
    __syncthreads();
    int woff = 0;
    for (int k = 0; k < wid; k++) woff += s_wt[k];
    if (woff) {
      for (int c = 0; c < 270; c += 64) {
        const int act = (c + lane) < 270;
        const int r = wid * 270 + c + lane;
        if (act) s_p[r + 1] += woff;
      }
    }
    if (tid == 0) s_p[0] = 0;
    __syncthreads();
  }
  const int total = s_wt[0] + s_wt[1] + s_wt[2] + s_wt[3];

  // ---- phase C: 256 queries ----
  {
    const int qi = (sub & 7) * 256 + tid;   // 0..2047 within side
    float r0 = 0, r1 = 0, r2 = 0, voff = 0, uoff = 0, o5 = 0, o6 = 0, o7 = 0;
    if (isfg) {
      float uf = ufg[n * FGN + qi];
      int rk = (int)(uf * smi.cntf);               // fp32 mul + trunc, matches ref
      int cm = smi.cnt_fg - 1; if (rk > cm) rk = cm;
      int lo = smi.v0m, hi = smi.v1m + 1;
      while (hi - lo > 1) { int mid = (lo + hi) >> 1; if (s_p[mid] <= rk) lo = mid; else hi = mid; }
      int v = lo, rem = rk - s_p[v];
      const uint4* row4 = (const uint4*)(bmn + v * WPR);
      int w4 = rumin[v] >> 7;
      int u = 0;
      for (;; w4++) {
        uint4 x = row4[w4];
        int c0 = __popc(x.x), c1 = __popc(x.y), c2 = __popc(x.z), c3 = __popc(x.w);
        int t = c0 + c1 + c2 + c3;
        if (rem < t) {
          unsigned int word; int wi;
          if (rem < c0) { word = x.x; wi = 0; }
          else if (rem < c0 + c1) { word = x.y; wi = 1; rem -= c0; }
          else if (rem < c0 + c1 + c2) { word = x.z; wi = 2; rem -= c0 + c1; }
          else { word = x.w; wi = 3; rem -= c0 + c1 + c2; }
          while (rem--) word &= word - 1;
          u = ((w4 * 4 + wi) << 5) + __ffs(word) - 1;
          break;
        }
        rem -= t;
      }
      long long pos = (long long)v * UMAX + u;
      r0 = img[pos * 3]; r1 = img[pos * 3 + 1]; r2 = img[pos * 3 + 2];
      voff = ((float)v - (float)smi.v0e - smi.vc) * (1.0f / 128.0f);
      uoff = ((float)u - (float)smi.u0e - smi.uc) * (1.0f / 128.0f);
      float* o = out + ((long long)(n * NPT + qi)) * 8;
      o[0] = r0; o[1] = r1; o[2] = r2; o[3] = voff; o[4] = uoff; o[5] = 0.f; o[6] = 0.f; o[7] = 0.f;
    } else {
      if (total > 0) {
        float ub = ubg[n * BGN + qi];
        int rk = (int)(ub * (float)total);
        int cm = total - 1; if (rk > cm) rk = cm;
        int lo = smi.v0e, hi = smi.v1e;
        while (hi - lo > 1) { int mid = (lo + hi) >> 1; if (s_p[mid] <= rk) lo = mid; else hi = mid; }
        int v = lo, rem = rk - s_p[v];
        const uint4* row4 = (const uint4*)(bmn + v * WPR);
        const int a = smi.u0e, b = smi.u1e;
        int u = 0;
        for (int w4 = a >> 7; ; w4++) {
          uint4 x = row4[w4];
          int base = w4 << 2;
          unsigned int b0 = (~x.x) & rangemask(base + 0, a, b);
          unsigned int b1 = (~x.y) & rangemask(base + 1, a, b);
          unsigned int b2 = (~x.z) & rangemask(base + 2, a, b);
          unsigned int b3 = (~x.w) & rangemask(base + 3, a, b);
          int c0 = __popc(b0), c1 = __popc(b1), c2 = __popc(b2), c3 = __popc(b3);
          int t = c0 + c1 + c2 + c3;
          if (rem < t) {
            unsigned int word; int wi;
            if (rem < c0) { word = b0; wi = 0; }
            else if (rem < c0 + c1) { word = b1; wi = 1; rem -= c0; }
            else if (rem < c0 + c1 + c2) { word = b2; wi = 2; rem -= c0 + c1; }
            else { word = b3; wi = 3; rem -= c0 + c1 + c2; }
            while (rem--) word &= word - 1;
            u = ((base + wi) << 5) + __ffs(word) - 1;
            break;
          }
          rem -= t;
        }
        long long pos = (long long)v * UMAX + u;
        r0 = img[pos * 3]; r1 = img[pos * 3 + 1]; r2 = img[pos * 3 + 2];
        voff = ((float)v - (float)smi.v0e - smi.vc) * (1.0f / 128.0f);
        uoff = ((float)u - (float)smi.u0e - smi.uc) * (1.0f / 128.0f);
        int uni = 0, wi = u >> 5, bi = u & 31;
        #pragma unroll
        for (int k2 = 0; k2 < NM; k2++)
          uni |= (int)((bmall[((long long)k2 * VMAX + v) * WPR + wi] >> bi) & 1u);
        const float* e = cat + (uni ? 6 : 0);
        o5 = e[0]; o6 = e[1]; o7 = e[2];
      }
      float* o = out + ((long long)(n * NPT + FGN + qi)) * 8;
      o[0] = r0; o[1] = r1; o[2] = r2; o[3] = voff; o[4] = uoff; o[5] = o5; o[6] = o6; o[7] = o7;
    }
  }
}

extern "C" void kernel_launch(void* const* d_in, const int* in_sizes, int n_in,
                              void* d_out, int out_size, void* d_ws, size_t ws_size,
                              hipStream_t stream) {
  const float* img  = (const float*)d_in[0];
  const unsigned int* masks = (const unsigned int*)d_in[1];
  const float* ufg  = (const float*)d_in[2];
  const float* ubg  = (const float*)d_in[3];
  const float* cat  = (const float*)d_in[4];
  float* out = (float*)d_out;
  char* ws = (char*)d_ws;

  hipLaunchKernelGGL(k_rows, dim3(NM * VMAX / 4), dim3(256), 0, stream, masks, ws);
  hipLaunchKernelGGL(k_samp, dim3(NM * 16), dim3(256), 0, stream,
                     img, ufg, ubg, cat, ws, out);
}

// Round 18
// 48.605 us; speedup vs baseline: 1.1148x; 1.1148x over previous
//
#include <hip/hip_runtime.h>
#include <math.h>

#define NM 16
#define VMAX 1080
#define UMAX 1920
#define WPR (UMAX/32)          // 60 words per row
#define FGN 2048
#define BGN 2048
#define NPT (FGN+BGN)          // 4096
#define PTS_FLOATS (NM*NPT*8)  // 524288

// ---- workspace layout (bytes) ----
#define OFF_BITMAP  0
#define BMBYTES     (NM*VMAX*WPR*4)
#define OFF_ROWCNT  (OFF_BITMAP + BMBYTES)
#define OFF_RUSUM   (OFF_ROWCNT + NM*VMAX*4)
#define OFF_RUMIN   (OFF_RUSUM  + NM*VMAX*4)
#define OFF_RUMAX   (OFF_RUMIN  + NM*VMAX*4)
// end ~4.4 MB

struct SInfo {
  int v0e, v1e, u0e, u1e, cnt_fg, v0m, v1m;
  float cntf, vc, uc;
};

__device__ inline unsigned int rangemask(int widx, int a, int b) {
  int lo = widx << 5, hi = lo + 32;
  if (b <= lo || a >= hi) return 0u;
  unsigned int m = 0xFFFFFFFFu;
  if (a > lo) m &= 0xFFFFFFFFu << (a - lo);
  if (b < hi) m &= (1u << (b - lo)) - 1u;
  return m;
}

// 4 waves per block, one wave per (mask,row); lane w owns bitmap word w.
// Masks are 4-byte elements (bool -> int32 per harness; f32 covered by
// dword != 0). r16-proven structure; PP removed (closed-form bg counts).
__global__ __launch_bounds__(256) void k_rows(const unsigned int* __restrict__ masks,
                                              char* ws) {
  const int R = blockIdx.x * 4 + (threadIdx.x >> 6);  // 0..NM*VMAX-1
  const int lane = threadIdx.x & 63;
  const int w = lane;
  unsigned int word = 0;
  if (w < WPR) {
    const uint4* p = (const uint4*)(masks + (long long)R * UMAX) + w * 8;
    #pragma unroll
    for (int t = 0; t < 8; t++) {
      uint4 x = p[t];
      unsigned int nib = (x.x ? 1u : 0u) | (x.y ? 2u : 0u) | (x.z ? 4u : 0u) | (x.w ? 8u : 0u);
      word |= nib << (t * 4);
    }
    ((unsigned int*)(ws + OFF_BITMAP))[(long long)R * WPR + w] = word;
  }
  int cnt = __popc(word);
  int usum = 0, umin = 0x7FFFFFFF, umax = -1;
  if (word) {
    umin = (w << 5) + __ffs(word) - 1;
    umax = (w << 5) + 31 - __clz(word);
    int bitsum = __popc(word & 0xAAAAAAAAu)
               + 2  * __popc(word & 0xCCCCCCCCu)
               + 4  * __popc(word & 0xF0F0F0F0u)
               + 8  * __popc(word & 0xFF00FF00u)
               + 16 * __popc(word & 0xFFFF0000u);
    usum = (w << 5) * cnt + bitsum;
  }
  for (int off = 32; off > 0; off >>= 1) {
    cnt  += __shfl_xor(cnt, off);
    usum += __shfl_xor(usum, off);
    umin = min(umin, __shfl_xor(umin, off));
    umax = max(umax, __shfl_xor(umax, off));
  }
  if (lane == 0) {
    ((int*)(ws + OFF_ROWCNT))[R] = cnt;
    ((int*)(ws + OFF_RUSUM))[R] = usum;
    ((int*)(ws + OFF_RUMIN))[R] = umin;
    ((int*)(ws + OFF_RUMAX))[R] = umax;
  }
}

// 256 blocks x 256 threads; 16 blocks per mask (8 fg + 8 bg), 256 queries each.
// Phase A: per-block bbox/centroid/crop reduce (redundant, L2-hot).
// Phase B: in-LDS two-level prefix scan; bg row counts CLOSED-FORM:
//   every mask pixel is in [u0,u1] with u0e<=u0, so mask-in-[a,b) =
//   rowcnt[r] - (bits >= b), and bits >= b exist only in the right-clamp
//   case b==UMAX-1 where it's exactly bit 1919 <=> rumax[r] >= b.
// Phase C: 256 rank-select queries (bit-exact logic).
__global__ __launch_bounds__(256) void k_samp(const float* __restrict__ img,
                                              const float* __restrict__ ufg,
                                              const float* __restrict__ ubg,
                                              const float* __restrict__ cat,
                                              char* ws, float* __restrict__ out) {
  __shared__ int s_p[VMAX + 1];
  __shared__ int s_wt[4];
  __shared__ long long s_vs[4], s_us[4];
  __shared__ int s_cnt[4], s_v0[4], s_v1[4], s_u0[4], s_u1[4];
  __shared__ SInfo smi;
  const int n = blockIdx.x >> 4, sub = blockIdx.x & 15;
  const bool isfg = sub < 8;
  const int tid = threadIdx.x, wid = tid >> 6, lane = tid & 63;
  const int* rowcnt = (const int*)(ws + OFF_ROWCNT) + n * VMAX;
  const int* rusum  = (const int*)(ws + OFF_RUSUM)  + n * VMAX;
  const int* rumin  = (const int*)(ws + OFF_RUMIN)  + n * VMAX;
  const int* rumax  = (const int*)(ws + OFF_RUMAX)  + n * VMAX;
  const unsigned int* bmall = (const unsigned int*)(ws + OFF_BITMAP);
  const unsigned int* bmn = bmall + (long long)n * VMAX * WPR;

  // ---- phase A: bbox + centroid reduce ----
  {
    int cnt = 0, v0 = 0x7FFFFFFF, v1 = -1, u0 = 0x7FFFFFFF, u1 = -1;
    long long vsum = 0, usum = 0;
    for (int v = tid; v < VMAX; v += 256) {
      int c = rowcnt[v];
      if (c > 0) { v0 = min(v0, v); v1 = max(v1, v); u0 = min(u0, rumin[v]); u1 = max(u1, rumax[v]); }
      cnt += c; vsum += (long long)c * v; usum += (long long)rusum[v];
    }
    for (int off = 32; off > 0; off >>= 1) {
      cnt  += __shfl_xor(cnt, off);
      vsum += __shfl_xor(vsum, off);
      usum += __shfl_xor(usum, off);
      v0 = min(v0, __shfl_xor(v0, off));
      v1 = max(v1, __shfl_xor(v1, off));
      u0 = min(u0, __shfl_xor(u0, off));
      u1 = max(u1, __shfl_xor(u1, off));
    }
    if (lane == 0) {
      s_cnt[wid] = cnt; s_vs[wid] = vsum; s_us[wid] = usum;
      s_v0[wid] = v0; s_v1[wid] = v1; s_u0[wid] = u0; s_u1[wid] = u1;
    }
    __syncthreads();
    if (wid == 0) {
      int c2 = (lane < 4) ? s_cnt[lane] : 0;
      long long vs2 = (lane < 4) ? s_vs[lane] : 0, us2 = (lane < 4) ? s_us[lane] : 0;
      int a0 = (lane < 4) ? s_v0[lane] : 0x7FFFFFFF, a1 = (lane < 4) ? s_v1[lane] : -1;
      int b0 = (lane < 4) ? s_u0[lane] : 0x7FFFFFFF, b1 = (lane < 4) ? s_u1[lane] : -1;
      for (int off = 1; off <= 2; off <<= 1) {
        c2 += __shfl_xor(c2, off);
        vs2 += __shfl_xor(vs2, off);
        us2 += __shfl_xor(us2, off);
        a0 = min(a0, __shfl_xor(a0, off));
        a1 = max(a1, __shfl_xor(a1, off));
        b0 = min(b0, __shfl_xor(b0, off));
        b1 = max(b1, __shfl_xor(b1, off));
      }
      if (lane == 0) {
        int vlen = a1 + 1 - a0, ulen = b1 + 1 - b0;
        int dv = (int)floorf(0.2f * (float)vlen);      // replicate f32 floor exactly
        int du = (int)floorf(0.2f * (float)ulen);
        smi.v0e = max(0, a0 - dv); smi.v1e = min(a1 + 1 + dv, VMAX - 1);
        smi.u0e = max(0, b0 - du); smi.u1e = min(b1 + 1 + du, UMAX - 1);
        smi.cnt_fg = c2; smi.cntf = (float)c2;
        smi.vc = (float)((double)vs2 / (double)c2) - (float)smi.v0e;
        smi.uc = (float)((double)us2 / (double)c2) - (float)smi.u0e;
        smi.v0m = a0; smi.v1m = a1;
        if (sub == 0) {
          float* xy = out + PTS_FLOATS + n * 4;
          xy[0] = (float)b0 / (float)UMAX; xy[1] = (float)a0 / (float)VMAX;
          xy[2] = (float)b1 / (float)UMAX; xy[3] = (float)a1 / (float)VMAX;
        }
      }
    }
    __syncthreads();
  }

  // ---- phase B: two-level scan into s_p[0..1080] (bg rows closed-form) ----
  {
    const int a = smi.u0e, b = smi.u1e;
    int wbase = 0;
    for (int c = 0; c < 270; c += 64) {
      const int act = (c + lane) < 270;
      const int r = wid * 270 + c + lane;
      int s = 0;
      if (act) {
        if (isfg) {
          s = rowcnt[r];
        } else if (r >= smi.v0e && r < smi.v1e && b > a) {
          s = (b - a) - rowcnt[r] + ((rumax[r] >= b) ? 1 : 0);
        }
      }
      for (int d = 1; d < 64; d <<= 1) { int t = __shfl_up(s, d); if (lane >= d) s += t; }
      if (act) s_p[r + 1] = wbase + s;
      wbase += __shfl(s, 63);
    }
    if (lane == 0) s_wt[wid] = wbase;
    __syncthreads();
    int woff = 0;
    for (int k = 0; k < wid; k++) woff += s_wt[k];
    if (woff) {
      for (int c = 0; c < 270; c += 64) {
        const int act = (c + lane) < 270;
        const int r = wid * 270 + c + lane;
        if (act) s_p[r + 1] += woff;
      }
    }
    if (tid == 0) s_p[0] = 0;
    __syncthreads();
  }
  const int total = s_wt[0] + s_wt[1] + s_wt[2] + s_wt[3];

  // ---- phase C: 256 queries ----
  {
    const int qi = (sub & 7) * 256 + tid;   // 0..2047 within side
    float r0 = 0, r1 = 0, r2 = 0, voff = 0, uoff = 0, o5 = 0, o6 = 0, o7 = 0;
    if (isfg) {
      float uf = ufg[n * FGN + qi];
      int rk = (int)(uf * smi.cntf);               // fp32 mul + trunc, matches ref
      int cm = smi.cnt_fg - 1; if (rk > cm) rk = cm;
      int lo = smi.v0m, hi = smi.v1m + 1;
      while (hi - lo > 1) { int mid = (lo + hi) >> 1; if (s_p[mid] <= rk) lo = mid; else hi = mid; }
      int v = lo, rem = rk - s_p[v];
      const uint4* row4 = (const uint4*)(bmn + v * WPR);
      int w4 = rumin[v] >> 7;
      int u = 0;
      for (;; w4++) {
        uint4 x = row4[w4];
        int c0 = __popc(x.x), c1 = __popc(x.y), c2 = __popc(x.z), c3 = __popc(x.w);
        int t = c0 + c1 + c2 + c3;
        if (rem < t) {
          unsigned int word; int wi;
          if (rem < c0) { word = x.x; wi = 0; }
          else if (rem < c0 + c1) { word = x.y; wi = 1; rem -= c0; }
          else if (rem < c0 + c1 + c2) { word = x.z; wi = 2; rem -= c0 + c1; }
          else { word = x.w; wi = 3; rem -= c0 + c1 + c2; }
          while (rem--) word &= word - 1;
          u = ((w4 * 4 + wi) << 5) + __ffs(word) - 1;
          break;
        }
        rem -= t;
      }
      long long pos = (long long)v * UMAX + u;
      r0 = img[pos * 3]; r1 = img[pos * 3 + 1]; r2 = img[pos * 3 + 2];
      voff = ((float)v - (float)smi.v0e - smi.vc) * (1.0f / 128.0f);
      uoff = ((float)u - (float)smi.u0e - smi.uc) * (1.0f / 128.0f);
      float* o = out + ((long long)(n * NPT + qi)) * 8;
      o[0] = r0; o[1] = r1; o[2] = r2; o[3] = voff; o[4] = uoff; o[5] = 0.f; o[6] = 0.f; o[7] = 0.f;
    } else {
      if (total > 0) {
        float ub = ubg[n * BGN + qi];
        int rk = (int)(ub * (float)total);
        int cm = total - 1; if (rk > cm) rk = cm;
        int lo = smi.v0e, hi = smi.v1e;
        while (hi - lo > 1) { int mid = (lo + hi) >> 1; if (s_p[mid] <= rk) lo = mid; else hi = mid; }
        int v = lo, rem = rk - s_p[v];
        const uint4* row4 = (const uint4*)(bmn + v * WPR);
        const int a = smi.u0e, b = smi.u1e;
        int u = 0;
        for (int w4 = a >> 7; ; w4++) {
          uint4 x = row4[w4];
          int base = w4 << 2;
          unsigned int b0 = (~x.x) & rangemask(base + 0, a, b);
          unsigned int b1 = (~x.y) & rangemask(base + 1, a, b);
          unsigned int b2 = (~x.z) & rangemask(base + 2, a, b);
          unsigned int b3 = (~x.w) & rangemask(base + 3, a, b);
          int c0 = __popc(b0), c1 = __popc(b1), c2 = __popc(b2), c3 = __popc(b3);
          int t = c0 + c1 + c2 + c3;
          if (rem < t) {
            unsigned int word; int wi;
            if (rem < c0) { word = b0; wi = 0; }
            else if (rem < c0 + c1) { word = b1; wi = 1; rem -= c0; }
            else if (rem < c0 + c1 + c2) { word = b2; wi = 2; rem -= c0 + c1; }
            else { word = b3; wi = 3; rem -= c0 + c1 + c2; }
            while (rem--) word &= word - 1;
            u = ((base + wi) << 5) + __ffs(word) - 1;
            break;
          }
          rem -= t;
        }
        long long pos = (long long)v * UMAX + u;
        r0 = img[pos * 3]; r1 = img[pos * 3 + 1]; r2 = img[pos * 3 + 2];
        voff = ((float)v - (float)smi.v0e - smi.vc) * (1.0f / 128.0f);
        uoff = ((float)u - (float)smi.u0e - smi.uc) * (1.0f / 128.0f);
        int uni = 0, wi = u >> 5, bi = u & 31;
        #pragma unroll
        for (int k2 = 0; k2 < NM; k2++)
          uni |= (int)((bmall[((long long)k2 * VMAX + v) * WPR + wi] >> bi) & 1u);
        const float* e = cat + (uni ? 6 : 0);
        o5 = e[0]; o6 = e[1]; o7 = e[2];
      }
      float* o = out + ((long long)(n * NPT + FGN + qi)) * 8;
      o[0] = r0; o[1] = r1; o[2] = r2; o[3] = voff; o[4] = uoff; o[5] = o5; o[6] = o6; o[7] = o7;
    }
  }
}

extern "C" void kernel_launch(void* const* d_in, const int* in_sizes, int n_in,
                              void* d_out, int out_size, void* d_ws, size_t ws_size,
                              hipStream_t stream) {
  const float* img  = (const float*)d_in[0];
  const unsigned int* masks = (const unsigned int*)d_in[1];
  const float* ufg  = (const float*)d_in[2];
  const float* ubg  = (const float*)d_in[3];
  const float* cat  = (const float*)d_in[4];
  float* out = (float*)d_out;
  char* ws = (char*)d_ws;

  hipLaunchKernelGGL(k_rows, dim3(NM * VMAX / 4), dim3(256), 0, stream, masks, ws);
  hipLaunchKernelGGL(k_samp, dim3(NM * 16), dim3(256), 0, stream,
                     img, ufg, ubg, cat, ws, out);
}

// Round 19
// 47.410 us; speedup vs baseline: 1.1429x; 1.0252x over previous
//
#include <hip/hip_runtime.h>
#include <math.h>

#define NM 16
#define VMAX 1080
#define UMAX 1920
#define WPR (UMAX/32)          // 60 words per row
#define FGN 2048
#define BGN 2048
#define NPT (FGN+BGN)          // 4096
#define PTS_FLOATS (NM*NPT*8)  // 524288

// ---- workspace layout (bytes) ----
#define OFF_BITMAP  0
#define BMBYTES     (NM*VMAX*WPR*4)
#define OFF_ROWCNT  (OFF_BITMAP + BMBYTES)
#define OFF_RUSUM   (OFF_ROWCNT + NM*VMAX*4)
#define OFF_RUMIN   (OFF_RUSUM  + NM*VMAX*4)
#define OFF_RUMAX   (OFF_RUMIN  + NM*VMAX*4)
// end ~4.4 MB

struct SInfo {
  int v0e, v1e, u0e, u1e, cnt_fg, v0m, v1m;
  float cntf, vc, uc;
};

__device__ inline unsigned int rangemask(int widx, int a, int b) {
  int lo = widx << 5, hi = lo + 32;
  if (b <= lo || a >= hi) return 0u;
  unsigned int m = 0xFFFFFFFFu;
  if (a > lo) m &= 0xFFFFFFFFu << (a - lo);
  if (b < hi) m &= (1u << (b - lo)) - 1u;
  return m;
}

// 4 waves per block, one wave per (mask,row); lane w owns bitmap word w.
// Masks are 4-byte elements (bool -> int32 per harness; f32 covered by
// dword != 0). r16-proven structure; closed-form bg counts (no PP).
__global__ __launch_bounds__(256) void k_rows(const unsigned int* __restrict__ masks,
                                              char* ws) {
  const int R = blockIdx.x * 4 + (threadIdx.x >> 6);  // 0..NM*VMAX-1
  const int lane = threadIdx.x & 63;
  const int w = lane;
  unsigned int word = 0;
  if (w < WPR) {
    const uint4* p = (const uint4*)(masks + (long long)R * UMAX) + w * 8;
    #pragma unroll
    for (int t = 0; t < 8; t++) {
      uint4 x = p[t];
      unsigned int nib = (x.x ? 1u : 0u) | (x.y ? 2u : 0u) | (x.z ? 4u : 0u) | (x.w ? 8u : 0u);
      word |= nib << (t * 4);
    }
    ((unsigned int*)(ws + OFF_BITMAP))[(long long)R * WPR + w] = word;
  }
  int cnt = __popc(word);
  int usum = 0, umin = 0x7FFFFFFF, umax = -1;
  if (word) {
    umin = (w << 5) + __ffs(word) - 1;
    umax = (w << 5) + 31 - __clz(word);
    int bitsum = __popc(word & 0xAAAAAAAAu)
               + 2  * __popc(word & 0xCCCCCCCCu)
               + 4  * __popc(word & 0xF0F0F0F0u)
               + 8  * __popc(word & 0xFF00FF00u)
               + 16 * __popc(word & 0xFFFF0000u);
    usum = (w << 5) * cnt + bitsum;
  }
  for (int off = 32; off > 0; off >>= 1) {
    cnt  += __shfl_xor(cnt, off);
    usum += __shfl_xor(usum, off);
    umin = min(umin, __shfl_xor(umin, off));
    umax = max(umax, __shfl_xor(umax, off));
  }
  if (lane == 0) {
    ((int*)(ws + OFF_ROWCNT))[R] = cnt;
    ((int*)(ws + OFF_RUSUM))[R] = usum;
    ((int*)(ws + OFF_RUMIN))[R] = umin;
    ((int*)(ws + OFF_RUMAX))[R] = umax;
  }
}

// 512 blocks x 256 threads; 32 blocks per mask (16 fg + 16 bg), 128 queries
// each (tid < 128) -> 2 blocks/CU for phase-C latency hiding.
// Phase A: per-block bbox/centroid/crop reduce (redundant, L2-hot, cheap).
// Phase B: in-LDS two-level prefix scan; bg row counts CLOSED-FORM:
//   mask-in-[a,b) = rowcnt[r] - (bits >= b), and bits >= b exist only in the
//   right-clamp case b==UMAX-1 where it's exactly bit 1919 <=> rumax[r] >= b.
// Phase C: 128 rank-select queries (bit-exact logic).
__global__ __launch_bounds__(256) void k_samp(const float* __restrict__ img,
                                              const float* __restrict__ ufg,
                                              const float* __restrict__ ubg,
                                              const float* __restrict__ cat,
                                              char* ws, float* __restrict__ out) {
  __shared__ int s_p[VMAX + 1];
  __shared__ int s_wt[4];
  __shared__ long long s_vs[4], s_us[4];
  __shared__ int s_cnt[4], s_v0[4], s_v1[4], s_u0[4], s_u1[4];
  __shared__ SInfo smi;
  const int n = blockIdx.x >> 5, sub = blockIdx.x & 31;
  const bool isfg = sub < 16;
  const int tid = threadIdx.x, wid = tid >> 6, lane = tid & 63;
  const int* rowcnt = (const int*)(ws + OFF_ROWCNT) + n * VMAX;
  const int* rusum  = (const int*)(ws + OFF_RUSUM)  + n * VMAX;
  const int* rumin  = (const int*)(ws + OFF_RUMIN)  + n * VMAX;
  const int* rumax  = (const int*)(ws + OFF_RUMAX)  + n * VMAX;
  const unsigned int* bmall = (const unsigned int*)(ws + OFF_BITMAP);
  const unsigned int* bmn = bmall + (long long)n * VMAX * WPR;

  // ---- phase A: bbox + centroid reduce ----
  {
    int cnt = 0, v0 = 0x7FFFFFFF, v1 = -1, u0 = 0x7FFFFFFF, u1 = -1;
    long long vsum = 0, usum = 0;
    for (int v = tid; v < VMAX; v += 256) {
      int c = rowcnt[v];
      if (c > 0) { v0 = min(v0, v); v1 = max(v1, v); u0 = min(u0, rumin[v]); u1 = max(u1, rumax[v]); }
      cnt += c; vsum += (long long)c * v; usum += (long long)rusum[v];
    }
    for (int off = 32; off > 0; off >>= 1) {
      cnt  += __shfl_xor(cnt, off);
      vsum += __shfl_xor(vsum, off);
      usum += __shfl_xor(usum, off);
      v0 = min(v0, __shfl_xor(v0, off));
      v1 = max(v1, __shfl_xor(v1, off));
      u0 = min(u0, __shfl_xor(u0, off));
      u1 = max(u1, __shfl_xor(u1, off));
    }
    if (lane == 0) {
      s_cnt[wid] = cnt; s_vs[wid] = vsum; s_us[wid] = usum;
      s_v0[wid] = v0; s_v1[wid] = v1; s_u0[wid] = u0; s_u1[wid] = u1;
    }
    __syncthreads();
    if (wid == 0) {
      int c2 = (lane < 4) ? s_cnt[lane] : 0;
      long long vs2 = (lane < 4) ? s_vs[lane] : 0, us2 = (lane < 4) ? s_us[lane] : 0;
      int a0 = (lane < 4) ? s_v0[lane] : 0x7FFFFFFF, a1 = (lane < 4) ? s_v1[lane] : -1;
      int b0 = (lane < 4) ? s_u0[lane] : 0x7FFFFFFF, b1 = (lane < 4) ? s_u1[lane] : -1;
      for (int off = 1; off <= 2; off <<= 1) {
        c2 += __shfl_xor(c2, off);
        vs2 += __shfl_xor(vs2, off);
        us2 += __shfl_xor(us2, off);
        a0 = min(a0, __shfl_xor(a0, off));
        a1 = max(a1, __shfl_xor(a1, off));
        b0 = min(b0, __shfl_xor(b0, off));
        b1 = max(b1, __shfl_xor(b1, off));
      }
      if (lane == 0) {
        int vlen = a1 + 1 - a0, ulen = b1 + 1 - b0;
        int dv = (int)floorf(0.2f * (float)vlen);      // replicate f32 floor exactly
        int du = (int)floorf(0.2f * (float)ulen);
        smi.v0e = max(0, a0 - dv); smi.v1e = min(a1 + 1 + dv, VMAX - 1);
        smi.u0e = max(0, b0 - du); smi.u1e = min(b1 + 1 + du, UMAX - 1);
        smi.cnt_fg = c2; smi.cntf = (float)c2;
        smi.vc = (float)((double)vs2 / (double)c2) - (float)smi.v0e;
        smi.uc = (float)((double)us2 / (double)c2) - (float)smi.u0e;
        smi.v0m = a0; smi.v1m = a1;
        if (sub == 0) {
          float* xy = out + PTS_FLOATS + n * 4;
          xy[0] = (float)b0 / (float)UMAX; xy[1] = (float)a0 / (float)VMAX;
          xy[2] = (float)b1 / (float)UMAX; xy[3] = (float)a1 / (float)VMAX;
        }
      }
    }
    __syncthreads();
  }

  // ---- phase B: two-level scan into s_p[0..1080] (bg rows closed-form) ----
  {
    const int a = smi.u0e, b = smi.u1e;
    int wbase = 0;
    for (int c = 0; c < 270; c += 64) {
      const int act = (c + lane) < 270;
      const int r = wid * 270 + c + lane;
      int s = 0;
      if (act) {
        if (isfg) {
          s = rowcnt[r];
        } else if (r >= smi.v0e && r < smi.v1e && b > a) {
          s = (b - a) - rowcnt[r] + ((rumax[r] >= b) ? 1 : 0);
        }
      }
      for (int d = 1; d < 64; d <<= 1) { int t = __shfl_up(s, d); if (lane >= d) s += t; }
      if (act) s_p[r + 1] = wbase + s;
      wbase += __shfl(s, 63);
    }
    if (lane == 0) s_wt[wid] = wbase;
    __syncthreads();
    int woff = 0;
    for (int k = 0; k < wid; k++) woff += s_wt[k];
    if (woff) {
      for (int c = 0; c < 270; c += 64) {
        const int act = (c + lane) < 270;
        const int r = wid * 270 + c + lane;
        if (act) s_p[r + 1] += woff;
      }
    }
    if (tid == 0) s_p[0] = 0;
    __syncthreads();
  }
  const int total = s_wt[0] + s_wt[1] + s_wt[2] + s_wt[3];

  // ---- phase C: 128 queries (tid < 128) ----
  if (tid < 128) {
    const int qi = (sub & 15) * 128 + tid;   // 0..2047 within side
    float r0 = 0, r1 = 0, r2 = 0, voff = 0, uoff = 0, o5 = 0, o6 = 0, o7 = 0;
    if (isfg) {
      float uf = ufg[n * FGN + qi];
      int rk = (int)(uf * smi.cntf);               // fp32 mul + trunc, matches ref
      int cm = smi.cnt_fg - 1; if (rk > cm) rk = cm;
      int lo = smi.v0m, hi = smi.v1m + 1;
      while (hi - lo > 1) { int mid = (lo + hi) >> 1; if (s_p[mid] <= rk) lo = mid; else hi = mid; }
      int v = lo, rem = rk - s_p[v];
      const uint4* row4 = (const uint4*)(bmn + v * WPR);
      int w4 = rumin[v] >> 7;
      int u = 0;
      for (;; w4++) {
        uint4 x = row4[w4];
        int c0 = __popc(x.x), c1 = __popc(x.y), c2 = __popc(x.z), c3 = __popc(x.w);
        int t = c0 + c1 + c2 + c3;
        if (rem < t) {
          unsigned int word; int wi;
          if (rem < c0) { word = x.x; wi = 0; }
          else if (rem < c0 + c1) { word = x.y; wi = 1; rem -= c0; }
          else if (rem < c0 + c1 + c2) { word = x.z; wi = 2; rem -= c0 + c1; }
          else { word = x.w; wi = 3; rem -= c0 + c1 + c2; }
          while (rem--) word &= word - 1;
          u = ((w4 * 4 + wi) << 5) + __ffs(word) - 1;
          break;
        }
        rem -= t;
      }
      long long pos = (long long)v * UMAX + u;
      r0 = img[pos * 3]; r1 = img[pos * 3 + 1]; r2 = img[pos * 3 + 2];
      voff = ((float)v - (float)smi.v0e - smi.vc) * (1.0f / 128.0f);
      uoff = ((float)u - (float)smi.u0e - smi.uc) * (1.0f / 128.0f);
      float* o = out + ((long long)(n * NPT + qi)) * 8;
      o[0] = r0; o[1] = r1; o[2] = r2; o[3] = voff; o[4] = uoff; o[5] = 0.f; o[6] = 0.f; o[7] = 0.f;
    } else {
      if (total > 0) {
        float ub = ubg[n * BGN + qi];
        int rk = (int)(ub * (float)total);
        int cm = total - 1; if (rk > cm) rk = cm;
        int lo = smi.v0e, hi = smi.v1e;
        while (hi - lo > 1) { int mid = (lo + hi) >> 1; if (s_p[mid] <= rk) lo = mid; else hi = mid; }
        int v = lo, rem = rk - s_p[v];
        const uint4* row4 = (const uint4*)(bmn + v * WPR);
        const int a = smi.u0e, b = smi.u1e;
        int u = 0;
        for (int w4 = a >> 7; ; w4++) {
          uint4 x = row4[w4];
          int base = w4 << 2;
          unsigned int b0 = (~x.x) & rangemask(base + 0, a, b);
          unsigned int b1 = (~x.y) & rangemask(base + 1, a, b);
          unsigned int b2 = (~x.z) & rangemask(base + 2, a, b);
          unsigned int b3 = (~x.w) & rangemask(base + 3, a, b);
          int c0 = __popc(b0), c1 = __popc(b1), c2 = __popc(b2), c3 = __popc(b3);
          int t = c0 + c1 + c2 + c3;
          if (rem < t) {
            unsigned int word; int wi;
            if (rem < c0) { word = b0; wi = 0; }
            else if (rem < c0 + c1) { word = b1; wi = 1; rem -= c0; }
            else if (rem < c0 + c1 + c2) { word = b2; wi = 2; rem -= c0 + c1; }
            else { word = b3; wi = 3; rem -= c0 + c1 + c2; }
            while (rem--) word &= word - 1;
            u = ((base + wi) << 5) + __ffs(word) - 1;
            break;
          }
          rem -= t;
        }
        long long pos = (long long)v * UMAX + u;
        r0 = img[pos * 3]; r1 = img[pos * 3 + 1]; r2 = img[pos * 3 + 2];
        voff = ((float)v - (float)smi.v0e - smi.vc) * (1.0f / 128.0f);
        uoff = ((float)u - (float)smi.u0e - smi.uc) * (1.0f / 128.0f);
        int uni = 0, wi = u >> 5, bi = u & 31;
        #pragma unroll
        for (int k2 = 0; k2 < NM; k2++)
          uni |= (int)((bmall[((long long)k2 * VMAX + v) * WPR + wi] >> bi) & 1u);
        const float* e = cat + (uni ? 6 : 0);
        o5 = e[0]; o6 = e[1]; o7 = e[2];
      }
      float* o = out + ((long long)(n * NPT + FGN + qi)) * 8;
      o[0] = r0; o[1] = r1; o[2] = r2; o[3] = voff; o[4] = uoff; o[5] = o5; o[6] = o6; o[7] = o7;
    }
  }
}

extern "C" void kernel_launch(void* const* d_in, const int* in_sizes, int n_in,
                              void* d_out, int out_size, void* d_ws, size_t ws_size,
                              hipStream_t stream) {
  const float* img  = (const float*)d_in[0];
  const unsigned int* masks = (const unsigned int*)d_in[1];
  const float* ufg  = (const float*)d_in[2];
  const float* ubg  = (const float*)d_in[3];
  const float* cat  = (const float*)d_in[4];
  float* out = (float*)d_out;
  char* ws = (char*)d_ws;

  hipLaunchKernelGGL(k_rows, dim3(NM * VMAX / 4), dim3(256), 0, stream, masks, ws);
  hipLaunchKernelGGL(k_samp, dim3(NM * 32), dim3(256), 0, stream,
                     img, ufg, ubg, cat, ws, out);
}